// Round 1
// baseline (209.924 us; speedup 1.0000x reference)
//
#include <hip/hip_runtime.h>

// Segment-mean pool: x [N][128] f32, batch [N] int (sorted, values in [0,16)),
// out [16][128] f32 = segment_sum(x)/max(count,1).

#define D       128
#define D4      32          // D/4 float4 per row
#define BSEG    16
#define THREADS 256
#define ROWS_PER_ITER 8     // THREADS / D4

__global__ __launch_bounds__(THREADS) void pool_sum_kernel(
    const float* __restrict__ x,
    const int*   __restrict__ batch,
    float*       __restrict__ sums,    // [BSEG*D] global accumulator (zeroed)
    float*       __restrict__ counts,  // [BSEG]   global accumulator (zeroed)
    int N, int nblocks)
{
    __shared__ float lds_sum[BSEG][D];
    __shared__ float lds_cnt[BSEG];

    const int tid = threadIdx.x;

    // zero the block-local accumulators
    for (int i = tid; i < BSEG * D; i += THREADS) ((float*)lds_sum)[i] = 0.0f;
    if (tid < BSEG) lds_cnt[tid] = 0.0f;
    __syncthreads();

    // contiguous row chunk per block (exploits sortedness of batch)
    const long chunk = ((long)N + nblocks - 1) / nblocks;
    const long r0 = (long)blockIdx.x * chunk;
    const long r1 = (r0 + chunk < (long)N) ? (r0 + chunk) : (long)N;

    const int col4  = tid & (D4 - 1);   // which float4 of the row
    const int rlane = tid >> 5;         // 0..7: row offset within iteration

    const float4* __restrict__ x4 = (const float4*)x;

    float4 acc = make_float4(0.f, 0.f, 0.f, 0.f);
    int    cnt = 0;
    int    cur = -1;

    for (long r = r0 + rlane; r < r1; r += ROWS_PER_ITER) {
        int seg = batch[r];
        if (seg != cur) {
            if (cur >= 0) {   // flush previous segment's partial
                atomicAdd(&lds_sum[cur][col4 * 4 + 0], acc.x);
                atomicAdd(&lds_sum[cur][col4 * 4 + 1], acc.y);
                atomicAdd(&lds_sum[cur][col4 * 4 + 2], acc.z);
                atomicAdd(&lds_sum[cur][col4 * 4 + 3], acc.w);
                if (col4 == 0) atomicAdd(&lds_cnt[cur], (float)cnt);
            }
            acc = make_float4(0.f, 0.f, 0.f, 0.f);
            cnt = 0;
            cur = (seg >= 0 && seg < BSEG) ? seg : -1;   // defensive
        }
        if (cur >= 0) {
            float4 v = x4[r * D4 + col4];
            acc.x += v.x; acc.y += v.y; acc.z += v.z; acc.w += v.w;
            cnt++;
        }
    }
    if (cur >= 0) {
        atomicAdd(&lds_sum[cur][col4 * 4 + 0], acc.x);
        atomicAdd(&lds_sum[cur][col4 * 4 + 1], acc.y);
        atomicAdd(&lds_sum[cur][col4 * 4 + 2], acc.z);
        atomicAdd(&lds_sum[cur][col4 * 4 + 3], acc.w);
        if (col4 == 0) atomicAdd(&lds_cnt[cur], (float)cnt);
    }
    __syncthreads();

    // one global flush per block; skip zeros to cut atomic traffic
    for (int i = tid; i < BSEG * D; i += THREADS) {
        float v = ((float*)lds_sum)[i];
        if (v != 0.0f) atomicAdd(&sums[i], v);
    }
    if (tid < BSEG) {
        float c = lds_cnt[tid];
        if (c != 0.0f) atomicAdd(&counts[tid], c);
    }
}

__global__ __launch_bounds__(THREADS) void pool_div_kernel(
    const float* __restrict__ sums,
    const float* __restrict__ counts,
    float*       __restrict__ out)
{
    int i = blockIdx.x * THREADS + threadIdx.x;
    if (i < BSEG * D) {
        float c = counts[i / D];
        out[i] = sums[i] / fmaxf(c, 1.0f);
    }
}

extern "C" void kernel_launch(void* const* d_in, const int* in_sizes, int n_in,
                              void* d_out, int out_size, void* d_ws, size_t ws_size,
                              hipStream_t stream)
{
    const float* x     = (const float*)d_in[0];
    const int*   batch = (const int*)d_in[1];
    const int    N     = in_sizes[1];          // one id per row

    float* sums   = (float*)d_ws;              // [BSEG*D]
    float* counts = sums + BSEG * D;           // [BSEG]

    hipMemsetAsync(d_ws, 0, (BSEG * D + BSEG) * sizeof(float), stream);

    const int nblocks = 2048;
    pool_sum_kernel<<<nblocks, THREADS, 0, stream>>>(x, batch, sums, counts, N, nblocks);

    pool_div_kernel<<<(BSEG * D + THREADS - 1) / THREADS, THREADS, 0, stream>>>(
        sums, counts, (float*)d_out);
}